// Round 3
// baseline (826.863 us; speedup 1.0000x reference)
//
#include <hip/hip_runtime.h>

#define NB 2
#define NN 512
#define NC 256
#define OUTP 14
#define SS 28
#define CH_SPLIT 4
#define CH_PER_BLK (NC / CH_SPLIT)                     // 64
#define ELEMS_PER_BLK (CH_PER_BLK * OUTP * OUTP)       // 12544 = 256*49
#define POOL_PER_BOX (NC * OUTP * OUTP)                // 50176
#define POOL_TOTAL (NB * NN * POOL_PER_BOX)
#define BOX_OFF POOL_TOTAL
#define KEEP_OFF (POOL_TOTAL + NB * NN * 4)

// ---------------- K1: fused NMS (sort + suppression matrix + greedy), one block per batch ----
__global__ __launch_bounds__(512) void k_nms(const float* __restrict__ boxes,
                                             const float* __restrict__ scores,
                                             float* __restrict__ dout) {
    int b = blockIdx.x;
    int tid = threadIdx.x;
    __shared__ float sS[NN];
    __shared__ int sI[NN];
    __shared__ float4 sB[NN];
    __shared__ float sA[NN];
    __shared__ int sL[NN];
    __shared__ unsigned long long sup[NN][8];   // 32 KB
    __shared__ unsigned long long skw[8];
    __shared__ int korig[NN];

    sS[tid] = scores[b * NN + tid];
    sI[tid] = tid;
    __syncthreads();
    // bitonic sort: (score desc, idx asc) == stable argsort(-scores)
    for (int k = 2; k <= NN; k <<= 1) {
        for (int j = k >> 1; j > 0; j >>= 1) {
            int ixj = tid ^ j;
            if (ixj > tid) {
                float s1 = sS[tid], s2 = sS[ixj];
                int i1 = sI[tid], i2 = sI[ixj];
                bool lt = (s1 > s2) || (s1 == s2 && i1 < i2);
                bool up = ((tid & k) == 0);
                if (up ? !lt : lt) {
                    sS[tid] = s2; sS[ixj] = s1;
                    sI[tid] = i2; sI[ixj] = i1;
                }
            }
            __syncthreads();
        }
    }
    // sorted-order meta
    {
        int o = sI[tid];
        float4 bx = ((const float4*)boxes)[b * NN + o];  // cx,cy,w,h
        float w = bx.z, h = bx.w;
        float x1 = bx.x - w * 0.5f, y1 = bx.y - h * 0.5f;
        float x2 = bx.x + w * 0.5f, y2 = bx.y + h * 0.5f;
        float s = sqrtf(w * h);
        int lvl = (s < 112.f) ? 1 : ((s < 224.f) ? 2 : ((s < 448.f) ? 3 : 4));
        sB[tid] = make_float4(x1, y1, x2, y2);
        sA[tid] = (x2 - x1) * (y2 - y1);
        sL[tid] = lvl;
    }
    __syncthreads();
    // suppression matrix: row tid, 8 x u64 column words
    {
        float4 bi = sB[tid];
        float areai = sA[tid];
        int il = sL[tid];
        for (int cg = 0; cg < 8; ++cg) {
            unsigned long long m = 0ull;
            int jb = cg << 6;
#pragma unroll 4
            for (int k = 0; k < 64; ++k) {
                int j = jb + k;
                float4 bj = sB[j];
                float xx1 = fmaxf(bi.x, bj.x);
                float yy1 = fmaxf(bi.y, bj.y);
                float xx2 = fminf(bi.z, bj.z);
                float yy2 = fminf(bi.w, bj.w);
                float inter = fmaxf(xx2 - xx1, 0.0f) * fmaxf(yy2 - yy1, 0.0f);
                float denom = areai + sA[j] - inter + 1e-9f;
                bool sp = (j > tid) && (sL[j] == il) && ((inter / denom) > 0.5f);
                m |= sp ? (1ull << k) : 0ull;
            }
            sup[tid][cg] = m;
        }
    }
    __syncthreads();
    // greedy: wave 0 only, replicated-state (lane l owns keep-word l&7)
    if (tid < 64) {
        int myw = tid & 7;
        unsigned long long kwl = ~0ull;
        for (int w = 0; w < 8; ++w) {
            unsigned long long aw = __shfl(kwl, w);  // active word w (uniform)
            int ibase = w << 6;
            for (int bb = 0; bb < 64; ++bb) {
                int i = ibase + bb;
                unsigned long long rw = sup[i][w];
                unsigned long long rl = sup[i][myw];
                if ((aw >> bb) & 1ull) {
                    aw &= ~rw;
                    kwl &= ~rl;
                }
            }
        }
        if (tid < 8) skw[tid] = kwl;
    }
    __syncthreads();
    korig[sI[tid]] = (int)((skw[tid >> 6] >> (tid & 63)) & 1ull);
    __syncthreads();
    {
        float4 bx = ((const float4*)boxes)[b * NN + tid];
        float kf = korig[tid] ? 1.0f : 0.0f;
        float x1 = (bx.x - bx.z * 0.5f) * kf;
        float y1 = (bx.y - bx.w * 0.5f) * kf;
        float x2 = (bx.x + bx.z * 0.5f) * kf;
        float y2 = (bx.y + bx.w * 0.5f) * kf;
        ((float4*)(dout + BOX_OFF))[b * NN + tid] = make_float4(x1, y1, x2, y2);
        dout[KEEP_OFF + b * NN + tid] = kf;
    }
}

// ---------------- K2: ROI align, 4 blocks per box (64 channels each) ----------------
// Latency-bound on scattered L2 gathers -> explicit 4-wide load-phase/math-phase
// chunks give ~64 outstanding loads per thread (ILP), trading VGPRs for latency hiding.
__global__ void k_roi(const float* __restrict__ p4,
                      const float* __restrict__ p8,
                      const float* __restrict__ p16,
                      const float* __restrict__ p32,
                      const float* __restrict__ boxes,
                      float* __restrict__ dout) {
    int blk = blockIdx.x;              // box*CH_SPLIT + chunk
    int box = blk >> 2;
    int chunk = blk & 3;
    int b = box >> 9;
    float* obase = dout + (size_t)box * POOL_PER_BOX + (size_t)chunk * ELEMS_PER_BLK;
    float keepf = dout[KEEP_OFF + box];
    if (keepf < 0.5f) {
        float4 z = make_float4(0.f, 0.f, 0.f, 0.f);
        float4* o4 = (float4*)obase;
        for (int i = threadIdx.x; i < ELEMS_PER_BLK / 4; i += 256) o4[i] = z;
        return;
    }
    float4 bx = ((const float4*)boxes)[box];
    float w = bx.z, h = bx.w;
    float s = sqrtf(w * h);
    int lvl = (s < 112.f) ? 0 : ((s < 224.f) ? 1 : ((s < 448.f) ? 2 : 3));
    const float* feat = (lvl == 0) ? p4 : ((lvl == 1) ? p8 : ((lvl == 2) ? p16 : p32));
    int HW = 256 >> lvl;
    float inv = 1.0f / (float)(4 << lvl);
    int planesz = HW * HW;
    const float* plane0 = feat + (size_t)b * NC * planesz + (size_t)(chunk * CH_PER_BLK) * planesz;

    __shared__ int sX0[SS], sX1[SS], sY0[SS], sY1[SS];
    __shared__ float sLX[SS], sLY[SS];
    if (threadIdx.x < SS) {
        int t = threadIdx.x;
        float g = (t + 0.5f) * 0.5f;
        float x1r = (bx.x - w * 0.5f) * inv;
        float x2r = (bx.x + w * 0.5f) * inv;
        float bwr = (x2r - x1r) / 14.0f;
        float xs = fminf(fmaxf(x1r + g * bwr, 0.0f), (float)(HW - 1));
        float x0f = floorf(xs);
        int x0 = (int)x0f;
        sX0[t] = x0;
        sX1[t] = min(x0 + 1, HW - 1);
        sLX[t] = xs - x0f;
        float y1r = (bx.y - h * 0.5f) * inv;
        float y2r = (bx.y + h * 0.5f) * inv;
        float bhr = (y2r - y1r) / 14.0f;
        float ys = fminf(fmaxf(y1r + g * bhr, 0.0f), (float)(HW - 1));
        float y0f = floorf(ys);
        int y0 = (int)y0f;
        sY0[t] = y0 * HW;
        sY1[t] = min(y0 + 1, HW - 1) * HW;
        sLY[t] = ys - y0f;
    }
    __syncthreads();

    int tid = threadIdx.x;
    const int ITER = ELEMS_PER_BLK / 256;   // 49
#define U 4
    int k = 0;
    for (; k + U <= ITER; k += U) {
        const float* plu[U];
        int ixu[U], iyu[U];
        float f00[U][4], f01[U][4], f10[U][4], f11[U][4];
        // ---- load phase: issue all 16*U gathers ----
#pragma unroll
        for (int u = 0; u < U; ++u) {
            unsigned idx = tid + (unsigned)(k + u) * 256u;
            unsigned c = idx / 196u;
            unsigned p = idx - c * 196u;
            unsigned py = p / 14u;
            unsigned px = p - py * 14u;
            const float* pl = plane0 + (size_t)c * planesz;
            int ix = 2 * px, iy = 2 * py;
            plu[u] = pl; ixu[u] = ix; iyu[u] = iy;
#pragma unroll
            for (int dy = 0; dy < 2; ++dy) {
                int yr0 = sY0[iy + dy], yr1 = sY1[iy + dy];
#pragma unroll
                for (int dx = 0; dx < 2; ++dx) {
                    int x0 = sX0[ix + dx], x1 = sX1[ix + dx];
                    int si = dy * 2 + dx;
                    f00[u][si] = pl[yr0 + x0];
                    f01[u][si] = pl[yr0 + x1];
                    f10[u][si] = pl[yr1 + x0];
                    f11[u][si] = pl[yr1 + x1];
                }
            }
        }
        // ---- math phase ----
#pragma unroll
        for (int u = 0; u < U; ++u) {
            float acc = 0.0f;
#pragma unroll
            for (int dy = 0; dy < 2; ++dy) {
                float ly = sLY[iyu[u] + dy];
#pragma unroll
                for (int dx = 0; dx < 2; ++dx) {
                    float lx = sLX[ixu[u] + dx];
                    int si = dy * 2 + dx;
                    float top = f00[u][si] + lx * (f01[u][si] - f00[u][si]);
                    float bot = f10[u][si] + lx * (f11[u][si] - f10[u][si]);
                    acc += top + ly * (bot - top);
                }
            }
            obase[tid + (unsigned)(k + u) * 256u] = acc * 0.25f;
        }
    }
    // remainder (49 % 4 = 1 iteration)
    for (; k < ITER; ++k) {
        unsigned idx = tid + (unsigned)k * 256u;
        unsigned c = idx / 196u;
        unsigned p = idx - c * 196u;
        unsigned py = p / 14u;
        unsigned px = p - py * 14u;
        const float* pl = plane0 + (size_t)c * planesz;
        int ix = 2 * px, iy = 2 * py;
        float acc = 0.0f;
#pragma unroll
        for (int dy = 0; dy < 2; ++dy) {
            int yr0 = sY0[iy + dy], yr1 = sY1[iy + dy];
            float ly = sLY[iy + dy];
#pragma unroll
            for (int dx = 0; dx < 2; ++dx) {
                int x0 = sX0[ix + dx], x1 = sX1[ix + dx];
                float lx = sLX[ix + dx];
                float a = pl[yr0 + x0], bq = pl[yr0 + x1];
                float cq = pl[yr1 + x0], d = pl[yr1 + x1];
                float top = a + lx * (bq - a);
                float bot = cq + lx * (d - cq);
                acc += top + ly * (bot - top);
            }
        }
        obase[idx] = acc * 0.25f;
    }
#undef U
}

extern "C" void kernel_launch(void* const* d_in, const int* in_sizes, int n_in,
                              void* d_out, int out_size, void* d_ws, size_t ws_size,
                              hipStream_t stream) {
    const float* p4 = (const float*)d_in[0];
    const float* p8 = (const float*)d_in[1];
    const float* p16 = (const float*)d_in[2];
    const float* p32 = (const float*)d_in[3];
    const float* boxes = (const float*)d_in[4];
    const float* scores = (const float*)d_in[5];
    float* out = (float*)d_out;

    k_nms<<<NB, NN, 0, stream>>>(boxes, scores, out);
    k_roi<<<NB * NN * CH_SPLIT, 256, 0, stream>>>(p4, p8, p16, p32, boxes, out);
}

// Round 4
// 715.231 us; speedup vs baseline: 1.1561x; 1.1561x over previous
//
#include <hip/hip_runtime.h>

#define NB 2
#define NN 512
#define NC 256
#define OUTP 14
#define SS 28
#define CH_SPLIT 4
#define CH_PER_BLK (NC / CH_SPLIT)                     // 64
#define ELEMS_PER_BLK (CH_PER_BLK * OUTP * OUTP)       // 12544
#define POOL_PER_BOX (NC * OUTP * OUTP)                // 50176
#define POOL_TOTAL (NB * NN * POOL_PER_BOX)
#define BOX_OFF POOL_TOTAL
#define KEEP_OFF (POOL_TOTAL + NB * NN * 4)

#define GCH 8          // channels staged per LDS group
#define PATCH_MAX 1216 // per-channel patch floats; bound: (0.97a+2)(0.97b+2), ab<784, a<=131 -> <=~1000

// ---------------- K1: fused NMS (sort + suppression matrix + greedy), one block per batch ----
__global__ __launch_bounds__(512) void k_nms(const float* __restrict__ boxes,
                                             const float* __restrict__ scores,
                                             float* __restrict__ dout) {
    int b = blockIdx.x;
    int tid = threadIdx.x;
    __shared__ float sS[NN];
    __shared__ int sI[NN];
    __shared__ float4 sB[NN];
    __shared__ float sA[NN];
    __shared__ int sL[NN];
    __shared__ unsigned long long sup[NN][8];   // 32 KB
    __shared__ unsigned long long skw[8];
    __shared__ int korig[NN];

    sS[tid] = scores[b * NN + tid];
    sI[tid] = tid;
    __syncthreads();
    for (int k = 2; k <= NN; k <<= 1) {
        for (int j = k >> 1; j > 0; j >>= 1) {
            int ixj = tid ^ j;
            if (ixj > tid) {
                float s1 = sS[tid], s2 = sS[ixj];
                int i1 = sI[tid], i2 = sI[ixj];
                bool lt = (s1 > s2) || (s1 == s2 && i1 < i2);
                bool up = ((tid & k) == 0);
                if (up ? !lt : lt) {
                    sS[tid] = s2; sS[ixj] = s1;
                    sI[tid] = i2; sI[ixj] = i1;
                }
            }
            __syncthreads();
        }
    }
    {
        int o = sI[tid];
        float4 bx = ((const float4*)boxes)[b * NN + o];
        float w = bx.z, h = bx.w;
        float x1 = bx.x - w * 0.5f, y1 = bx.y - h * 0.5f;
        float x2 = bx.x + w * 0.5f, y2 = bx.y + h * 0.5f;
        float s = sqrtf(w * h);
        int lvl = (s < 112.f) ? 1 : ((s < 224.f) ? 2 : ((s < 448.f) ? 3 : 4));
        sB[tid] = make_float4(x1, y1, x2, y2);
        sA[tid] = (x2 - x1) * (y2 - y1);
        sL[tid] = lvl;
    }
    __syncthreads();
    {
        float4 bi = sB[tid];
        float areai = sA[tid];
        int il = sL[tid];
        for (int cg = 0; cg < 8; ++cg) {
            unsigned long long m = 0ull;
            int jb = cg << 6;
#pragma unroll 4
            for (int k = 0; k < 64; ++k) {
                int j = jb + k;
                float4 bj = sB[j];
                float xx1 = fmaxf(bi.x, bj.x);
                float yy1 = fmaxf(bi.y, bj.y);
                float xx2 = fminf(bi.z, bj.z);
                float yy2 = fminf(bi.w, bj.w);
                float inter = fmaxf(xx2 - xx1, 0.0f) * fmaxf(yy2 - yy1, 0.0f);
                float denom = areai + sA[j] - inter + 1e-9f;
                bool sp = (j > tid) && (sL[j] == il) && ((inter / denom) > 0.5f);
                m |= sp ? (1ull << k) : 0ull;
            }
            sup[tid][cg] = m;
        }
    }
    __syncthreads();
    if (tid < 64) {
        int myw = tid & 7;
        unsigned long long kwl = ~0ull;
        for (int w = 0; w < 8; ++w) {
            unsigned long long aw = __shfl(kwl, w);
            int ibase = w << 6;
            for (int bb = 0; bb < 64; ++bb) {
                int i = ibase + bb;
                unsigned long long rw = sup[i][w];
                unsigned long long rl = sup[i][myw];
                if ((aw >> bb) & 1ull) {
                    aw &= ~rw;
                    kwl &= ~rl;
                }
            }
        }
        if (tid < 8) skw[tid] = kwl;
    }
    __syncthreads();
    korig[sI[tid]] = (int)((skw[tid >> 6] >> (tid & 63)) & 1ull);
    __syncthreads();
    {
        float4 bx = ((const float4*)boxes)[b * NN + tid];
        float kf = korig[tid] ? 1.0f : 0.0f;
        float x1 = (bx.x - bx.z * 0.5f) * kf;
        float y1 = (bx.y - bx.w * 0.5f) * kf;
        float x2 = (bx.x + bx.z * 0.5f) * kf;
        float y2 = (bx.y + bx.w * 0.5f) * kf;
        ((float4*)(dout + BOX_OFF))[b * NN + tid] = make_float4(x1, y1, x2, y2);
        dout[KEEP_OFF + b * NN + tid] = kf;
    }
}

// ---------------- K2: ROI align via LDS patch staging ----------------
// One block per (box, 64-channel chunk). For each group of GCH channels: stage the
// unique feature patch into LDS with coalesced row loads, then compute 196 outputs
// per channel from LDS. Converts 16 scattered TA transactions/output into ~row loads.
__global__ __launch_bounds__(256) void k_roi(const float* __restrict__ p4,
                                             const float* __restrict__ p8,
                                             const float* __restrict__ p16,
                                             const float* __restrict__ p32,
                                             const float* __restrict__ boxes,
                                             float* __restrict__ dout) {
    int blk = blockIdx.x;
    int box = blk >> 2;
    int chunk = blk & 3;
    int b = box >> 9;
    int tid = threadIdx.x;
    float* obase = dout + (size_t)box * POOL_PER_BOX + (size_t)chunk * ELEMS_PER_BLK;
    float keepf = dout[KEEP_OFF + box];
    if (keepf < 0.5f) {
        float4 z = make_float4(0.f, 0.f, 0.f, 0.f);
        float4* o4 = (float4*)obase;
        for (int i = tid; i < ELEMS_PER_BLK / 4; i += 256) o4[i] = z;
        return;
    }
    float4 bx = ((const float4*)boxes)[box];
    float w = bx.z, h = bx.w;
    float s = sqrtf(w * h);
    int lvl = (s < 112.f) ? 0 : ((s < 224.f) ? 1 : ((s < 448.f) ? 2 : 3));
    const float* feat = (lvl == 0) ? p4 : ((lvl == 1) ? p8 : ((lvl == 2) ? p16 : p32));
    int HW = 256 >> lvl;
    float inv = 1.0f / (float)(4 << lvl);
    int planesz = HW * HW;
    const float* plane0 = feat + (size_t)b * NC * planesz + (size_t)(chunk * CH_PER_BLK) * planesz;

    // uniform patch bounds (samples are monotonic in t)
    float x1r = (bx.x - w * 0.5f) * inv;
    float bwr = w * inv / 14.0f;
    float y1r = (bx.y - h * 0.5f) * inv;
    float bhr = h * inv / 14.0f;
    float hwm1 = (float)(HW - 1);
    float xs_first = fminf(fmaxf(x1r + 0.25f * bwr, 0.0f), hwm1);
    float xs_last  = fminf(fmaxf(x1r + 13.75f * bwr, 0.0f), hwm1);
    float ys_first = fminf(fmaxf(y1r + 0.25f * bhr, 0.0f), hwm1);
    float ys_last  = fminf(fmaxf(y1r + 13.75f * bhr, 0.0f), hwm1);
    int x_lo = (int)floorf(xs_first);
    int x_hi = min((int)floorf(xs_last) + 1, HW - 1);
    int y_lo = (int)floorf(ys_first);
    int y_hi = min((int)floorf(ys_last) + 1, HW - 1);
    int PW = x_hi - x_lo + 1;
    int PH = y_hi - y_lo + 1;
    int cells = PW * PH;
    float invPW = 1.0f / (float)PW;

    __shared__ float patch[GCH * PATCH_MAX];  // 38912 B
    __shared__ int sXr0[SS], sXr1[SS], sYr0[SS], sYr1[SS];
    __shared__ float sLX[SS], sLY[SS];

    if (tid < SS) {
        int t = tid;
        float g = (t + 0.5f) * 0.5f;
        float xs = fminf(fmaxf(x1r + g * bwr, 0.0f), hwm1);
        float x0f = floorf(xs);
        int x0 = (int)x0f;
        sXr0[t] = x0 - x_lo;
        sXr1[t] = min(x0 + 1, HW - 1) - x_lo;
        sLX[t] = xs - x0f;
        float ys = fminf(fmaxf(y1r + g * bhr, 0.0f), hwm1);
        float y0f = floorf(ys);
        int y0 = (int)y0f;
        sYr0[t] = y0 - y_lo;
        sYr1[t] = min(y0 + 1, HW - 1) - y_lo;
        sLY[t] = ys - y0f;
    }
    // (first __syncthreads below covers these writes)

    const int base_gidx = y_lo * HW + x_lo;
    for (int grp = 0; grp < CH_PER_BLK / GCH; ++grp) {   // 8 groups
        // ---- stage GCH channel patches (coalesced row segments) ----
        const float* plg = plane0 + (size_t)(grp * GCH) * planesz;
#pragma unroll
        for (int g = 0; g < GCH; ++g) {
            const float* pl = plg + (size_t)g * planesz;
            float* dst = patch + g * PATCH_MAX;
            for (int i = tid; i < cells; i += 256) {
                int row = (int)(((float)i + 0.5f) * invPW);
                int col = i - row * PW;
                dst[i] = pl[base_gidx + row * HW + col];
            }
        }
        __syncthreads();
        // ---- compute GCH*196 outputs from LDS ----
        for (int i = tid; i < GCH * 196; i += 256) {
            int g = i / 196;
            int p = i - g * 196;
            int py = p / 14;
            int px = p - py * 14;
            const float* P = patch + g * PATCH_MAX;
            int ix = 2 * px, iy = 2 * py;
            float acc = 0.0f;
#pragma unroll
            for (int dy = 0; dy < 2; ++dy) {
                int r0 = sYr0[iy + dy] * PW;
                int r1 = sYr1[iy + dy] * PW;
                float ly = sLY[iy + dy];
#pragma unroll
                for (int dx = 0; dx < 2; ++dx) {
                    int c0 = sXr0[ix + dx];
                    int c1 = sXr1[ix + dx];
                    float lx = sLX[ix + dx];
                    float f00 = P[r0 + c0], f01 = P[r0 + c1];
                    float f10 = P[r1 + c0], f11 = P[r1 + c1];
                    float top = f00 + lx * (f01 - f00);
                    float bot = f10 + lx * (f11 - f10);
                    acc += top + ly * (bot - top);
                }
            }
            obase[grp * (GCH * 196) + i] = acc * 0.25f;
        }
        if (grp < CH_PER_BLK / GCH - 1) __syncthreads();
    }
}

extern "C" void kernel_launch(void* const* d_in, const int* in_sizes, int n_in,
                              void* d_out, int out_size, void* d_ws, size_t ws_size,
                              hipStream_t stream) {
    const float* p4 = (const float*)d_in[0];
    const float* p8 = (const float*)d_in[1];
    const float* p16 = (const float*)d_in[2];
    const float* p32 = (const float*)d_in[3];
    const float* boxes = (const float*)d_in[4];
    const float* scores = (const float*)d_in[5];
    float* out = (float*)d_out;

    k_nms<<<NB, NN, 0, stream>>>(boxes, scores, out);
    k_roi<<<NB * NN * CH_SPLIT, 256, 0, stream>>>(p4, p8, p16, p32, boxes, out);
}